// Round 1
// 8419.233 us; speedup vs baseline: 1.9888x; 1.9888x over previous
//
#include <hip/hip_runtime.h>

#define TT   1024
#define BB   64
#define DIN  256
#define HH   512
#define ROWS 8
#define HCW    36            // padded h-chunk stride in words (32 + 4)
#define HROW_W (16 * HCW)    // 576 words per staged h row
#define XROW_W 264           // staged x row stride in words (256 + 8)

// tanh via expf: avoids ocml tanhf slow path; clamp keeps exp finite
// (tanh(15) rounds to 1.0f exactly, so the clamp is value-preserving).
__device__ __forceinline__ float tanh_f(float x) {
    float xx = fminf(15.f, fmaxf(-15.f, x));
    float e2 = expf(2.f * xx);
    return 1.f - 2.f / (e2 + 1.f);
}

// Persistent kernel: 256 blocks (8 rowgrps x 32 colgrps), 1/CU. Block owns
// 8 batch rows x 16 h-cols (64 z-cols). Wh AND Wx slices in registers.
// Sync redesign vs previous version:
//  - h outputs stored write-through to L3 (relaxed agent atomic stores,
//    sc0 sc1) -> producer needs NO buffer_wbl2 (no RELEASE RMW).
//  - per-producer flags (plain relaxed agent stores, one 128B line per
//    rowgroup) replace the single fetch_add counter -> no L3 RMW
//    serialization; consumer wave0 polls all 32 flags in ONE wave-load.
//  - one acquire-agent fence (buffer_inv only) after poll, before the
//    plain float4 h-stage loads.
//  - x@Wx (K=256, no h dependence) computed from LDS-staged x BEFORE the
//    poll, filling straggler-wait time; serial K-loop is h-only (K=512).
__global__ __launch_bounds__(256, 1)
void lstm_persist(const float* __restrict__ x_all,  // [1024][64][256]
                  const float* __restrict__ W4,     // [768][2048]
                  const float* __restrict__ b4,     // [2048]
                  float* out,                        // [1024][64][512] + hx + cx
                  const float* h0,                   // [64][512] zeros
                  unsigned int* bar)                 // 8 rowgroups x 32 flags
{
    __shared__ float sH[ROWS * HROW_W];      // staged h_{t-1}, 18.4 KB
    __shared__ float sX[ROWS * XROW_W];      // staged x_t, 8.4 KB
    __shared__ float sP[ROWS * 64 * 20];     // K-split partials, 40 KB
    __shared__ float sC[ROWS * 16];          // c state, block-local

    const int tid = threadIdx.x;
    const int bid = blockIdx.x;
    const int rg  = bid & 7;                 // rowgrp
    const int cgb = bid >> 3;                // colgrp 0..31
    const int r0  = rg * ROWS;
    const int hc0 = cgb * 16;

    const int cg = tid & 15;                 // owns 4 z-cols
    const int kc = tid >> 4;                 // K-chunk 0..15
    const int l0 = cg * 4;
    const int gate = l0 >> 4;
    const int zc0 = gate * 512 + hc0 + (l0 & 15);

    unsigned int* flags = bar + rg * 32;     // one 128B line per rowgroup

    // ---- precomputed staging offsets (t-invariant) ----
    int hL[4], hG[4];                        // h: 1024 float4s, 4/thread
    #pragma unroll
    for (int s = 0; s < 4; ++s) {
        int j = tid + 256 * s;
        int row = j >> 7, kw = (j & 127) * 4;
        hL[s] = row * HROW_W + (kw >> 5) * HCW + (kw & 31);
        hG[s] = (r0 + row) * HH + kw;
    }
    int xL[2], xG[2];                        // x: 512 float4s, 2/thread
    #pragma unroll
    for (int s = 0; s < 2; ++s) {
        int j = tid + 256 * s;
        int row = j >> 6, kq = (j & 63) * 4;
        xL[s] = row * XROW_W + kq;
        xG[s] = (r0 + row) * DIN + kq;
    }

    // ---- one-time: Wh slice (rows DIN + kc*32..+31, cols zc0..+3) ----
    float4 w0[8], w1[8], w2[8], w3[8];
    #pragma unroll
    for (int k4 = 0; k4 < 8; ++k4) {
        const float* base = W4 + (size_t)(DIN + kc * 32 + 4 * k4) * 2048 + zc0;
        float4 t0 = *(const float4*)(base);
        float4 t1 = *(const float4*)(base + 2048);
        float4 t2 = *(const float4*)(base + 4096);
        float4 t3 = *(const float4*)(base + 6144);
        w0[k4] = make_float4(t0.x, t1.x, t2.x, t3.x);
        w1[k4] = make_float4(t0.y, t1.y, t2.y, t3.y);
        w2[k4] = make_float4(t0.z, t1.z, t2.z, t3.z);
        w3[k4] = make_float4(t0.w, t1.w, t2.w, t3.w);
    }
    // ---- one-time: Wx slice (rows kc*16..+15, cols zc0..+3), row-major ----
    float4 wx[16];
    #pragma unroll
    for (int kk = 0; kk < 16; ++kk)
        wx[kk] = *(const float4*)(W4 + (size_t)(kc * 16 + kk) * 2048 + zc0);

    float bias0 = 0.f, bias1 = 0.f, bias2 = 0.f, bias3 = 0.f;
    if (tid < 128) {
        sC[tid] = 0.f;
        int hc = tid & 15;
        bias0 = b4[0 * 512 + hc0 + hc];
        bias1 = b4[1 * 512 + hc0 + hc];
        bias2 = b4[2 * 512 + hc0 + hc];
        bias3 = b4[3 * 512 + hc0 + hc];
    }

    // ---- pre-stage x_0 ----
    #pragma unroll
    for (int s = 0; s < 2; ++s)
        *(float4*)&sX[xL[s]] = *(const float4*)(x_all + xG[s]);
    __syncthreads();

    for (int t = 0; t < TT; ++t) {
        // ---- (a) x-part partials (no h dependence) — fills poll wait ----
        float ac0[8], ac1[8], ac2[8], ac3[8];
        #pragma unroll
        for (int r = 0; r < ROWS; ++r) {
            const float* xp = &sX[r * XROW_W + kc * 16];
            float ax = 0.f, ay = 0.f, az = 0.f, aw = 0.f;
            #pragma unroll
            for (int q = 0; q < 4; ++q) {
                float4 x4 = *(const float4*)(xp + 4 * q);
                ax = fmaf(x4.x, wx[4*q+0].x, ax); ax = fmaf(x4.y, wx[4*q+1].x, ax);
                ax = fmaf(x4.z, wx[4*q+2].x, ax); ax = fmaf(x4.w, wx[4*q+3].x, ax);
                ay = fmaf(x4.x, wx[4*q+0].y, ay); ay = fmaf(x4.y, wx[4*q+1].y, ay);
                ay = fmaf(x4.z, wx[4*q+2].y, ay); ay = fmaf(x4.w, wx[4*q+3].y, ay);
                az = fmaf(x4.x, wx[4*q+0].z, az); az = fmaf(x4.y, wx[4*q+1].z, az);
                az = fmaf(x4.z, wx[4*q+2].z, az); az = fmaf(x4.w, wx[4*q+3].z, az);
                aw = fmaf(x4.x, wx[4*q+0].w, aw); aw = fmaf(x4.y, wx[4*q+1].w, aw);
                aw = fmaf(x4.z, wx[4*q+2].w, aw); aw = fmaf(x4.w, wx[4*q+3].w, aw);
            }
            ac0[r] = ax; ac1[r] = ay; ac2[r] = az; ac3[r] = aw;
        }

        // ---- (b) wait for h_{t-1}: wave0 polls 32 flags in parallel ----
        if (t > 0 && tid < 64) {
            unsigned v;
            do {
                v = __hip_atomic_load(&flags[tid & 31], __ATOMIC_RELAXED,
                                      __HIP_MEMORY_SCOPE_AGENT);
            } while (__any(v < (unsigned)t));
            // acquire: waitcnt + buffer_inv (L1/L2 invalidate, NO writeback);
            // makes the plain float4 h loads below read fresh L3 data.
            __builtin_amdgcn_fence(__ATOMIC_ACQUIRE, "agent");
        }
        __syncthreads();                                  // B1

        // ---- (d) stage h_{t-1} into LDS; issue x_{t+1} loads ----
        const float* hsrc = (t == 0) ? h0 : out + (size_t)(t - 1) * (BB * HH);
        #pragma unroll
        for (int s = 0; s < 4; ++s)
            *(float4*)&sH[hL[s]] = *(const float4*)(hsrc + hG[s]);
        float4 xr0, xr1;
        const bool havex = (t + 1 < TT);
        if (havex) {
            const float* xb = x_all + (size_t)(t + 1) * (BB * DIN);
            xr0 = *(const float4*)(xb + xG[0]);
            xr1 = *(const float4*)(xb + xG[1]);
        }
        __syncthreads();                                  // B2

        // ---- (f) h-part: continue accumulation over this thread's 32-K ----
        #pragma unroll
        for (int r = 0; r < ROWS; ++r) {
            const float* hp = &sH[r * HROW_W + kc * HCW];
            float ax = ac0[r], ay = ac1[r], az = ac2[r], aw = ac3[r];
            #pragma unroll
            for (int k4 = 0; k4 < 8; ++k4) {
                float4 h4 = *(const float4*)(hp + 4 * k4);
                ax = fmaf(h4.x, w0[k4].x, ax); ax = fmaf(h4.y, w0[k4].y, ax);
                ax = fmaf(h4.z, w0[k4].z, ax); ax = fmaf(h4.w, w0[k4].w, ax);
                ay = fmaf(h4.x, w1[k4].x, ay); ay = fmaf(h4.y, w1[k4].y, ay);
                ay = fmaf(h4.z, w1[k4].z, ay); ay = fmaf(h4.w, w1[k4].w, ay);
                az = fmaf(h4.x, w2[k4].x, az); az = fmaf(h4.y, w2[k4].y, az);
                az = fmaf(h4.z, w2[k4].z, az); az = fmaf(h4.w, w2[k4].w, az);
                aw = fmaf(h4.x, w3[k4].x, aw); aw = fmaf(h4.y, w3[k4].y, aw);
                aw = fmaf(h4.z, w3[k4].z, aw); aw = fmaf(h4.w, w3[k4].w, aw);
            }
            float* pp = &sP[(r * 64 + l0) * 20];
            pp[0 * 20 + ((kc + 5 * cg + 0) & 15)] = ax;
            pp[1 * 20 + ((kc + 5 * cg + 1) & 15)] = ay;
            pp[2 * 20 + ((kc + 5 * cg + 2) & 15)] = az;
            pp[3 * 20 + ((kc + 5 * cg + 3) & 15)] = aw;
        }
        if (havex) {                      // sX dead since B1; refill for t+1
            *(float4*)&sX[xL[0]] = xr0;
            *(float4*)&sX[xL[1]] = xr1;
        }
        __syncthreads();                                  // B3

        // ---- (h) reduce partials, gates, c/h update (128 threads) ----
        if (tid < 128) {
            int rr = tid >> 4;
            int hc = tid & 15;
            float z[4];
            #pragma unroll
            for (int g = 0; g < 4; ++g) {
                const float* pp = &sP[(rr * 64 + g * 16 + hc) * 20];
                float s = 0.f;
                #pragma unroll
                for (int q = 0; q < 4; ++q) {
                    int off = 4 * ((rr + q) & 3);
                    float4 a = *(const float4*)(pp + off);
                    s += ((a.x + a.y) + (a.z + a.w));
                }
                z[g] = s;
            }
            z[0] += bias0; z[1] += bias1; z[2] += bias2; z[3] += bias3;
            float f  = 1.f / (1.f + expf(-z[0]));
            float ii = 1.f / (1.f + expf(-z[1]));
            float gg = tanh_f(z[2]);
            float o  = 1.f / (1.f + expf(-z[3]));
            float cn = f * sC[rr * 16 + hc] + ii * gg;
            sC[rr * 16 + hc] = cn;
            float hn = o * tanh_f(cn);
            // write-through to L3 (sc0 sc1): cross-XCD visible with no wbl2
            __hip_atomic_store(out + ((size_t)t * BB + (r0 + rr)) * HH + hc0 + hc,
                               hn, __ATOMIC_RELAXED, __HIP_MEMORY_SCOPE_AGENT);
            if (t == TT - 1) {
                out[(size_t)TT * BB * HH + (size_t)(r0 + rr) * HH + hc0 + hc] = hn;            // hx
                out[(size_t)TT * BB * HH + BB * HH + (size_t)(r0 + rr) * HH + hc0 + hc] = cn;  // cx
            }
        }
        __syncthreads();   // B4: per-wave vmcnt(0) drains the agent stores

        // ---- arrive: plain relaxed store to own flag (no RMW, no wbl2) ----
        if (tid == 0) {
            asm volatile("" ::: "memory");   // keep store below the barrier
            __hip_atomic_store(&flags[cgb], (unsigned)(t + 1), __ATOMIC_RELAXED,
                               __HIP_MEMORY_SCOPE_AGENT);
        }
    }
}

extern "C" void kernel_launch(void* const* d_in, const int* in_sizes, int n_in,
                              void* d_out, int out_size, void* d_ws, size_t ws_size,
                              hipStream_t stream) {
    const float* x_all = (const float*)d_in[0];
    const float* W4    = (const float*)d_in[1];
    const float* b4    = (const float*)d_in[2];
    float* out = (float*)d_out;

    unsigned int* bar = (unsigned int*)d_ws;                    // 8 x 32 flags
    float* h0 = (float*)((char*)d_ws + 2048);                   // 64x512 zeros

    hipMemsetAsync(d_ws, 0, 2048 + (size_t)BB * HH * sizeof(float), stream);

    lstm_persist<<<dim3(256), dim3(256), 0, stream>>>(x_all, W4, b4, out, h0, bar);
}

// Round 4
// 6690.248 us; speedup vs baseline: 2.5028x; 1.2584x over previous
//
#include <hip/hip_runtime.h>

#define TT   1024
#define BB   64
#define DIN  256
#define HH   512
#define ROWS 8
#define HCW    36            // padded h-chunk stride in words (32 + 4)
#define HROW_W (16 * HCW)    // 576 words per staged h row
#define XROW_W 264           // staged x row stride in words (256 + 8)
#define EXQ  (BB * HH)       // 32768 tuples per parity buffer

typedef unsigned long long u64;

// tanh via expf: avoids ocml tanhf slow path; clamp keeps exp finite
// (tanh(15) rounds to 1.0f exactly, so the clamp is value-preserving).
__device__ __forceinline__ float tanh_f(float x) {
    float xx = fminf(15.f, fmaxf(-15.f, x));
    float e2 = expf(2.f * xx);
    return 1.f - 2.f / (e2 + 1.f);
}

// Persistent kernel: 256 blocks (8 rowgrps x 32 colgrps), 1/CU. Block owns
// 8 batch rows x 16 h-cols. Wh AND Wx slices in registers.
//
// vs r1 (8.4ms, passed): h exchange via SELF-VALIDATING 8B TUPLES
// (float h_bits | (t+1)<<32), double-buffered by t&1, agent-scope atomics:
//  - producer: one fire-and-forget atomic store per h value. NO vmcnt
//    drain, NO flag, NO release (tag+payload are one atomic word).
//  - consumer: per-tuple spin until seq==t; the data load IS the sync.
//    NO flag poll, NO acquire fence, NO buffer_inv -> L2 stays warm for x.
//  - collapses ~4 serialized L3 round trips per step into 1.
// Deadlock-proof: no probes, no grid barrier, no placement assumptions;
// dependency structure (rowgroup-internal) identical to the passing r1.
// Double-buffer safety: buffer b is rewritten at step t+2 only after its
// writer consumed h_{t+1} from ALL blocks, which requires every block to
// have produced h_{t+1}, which requires their step-t reads of buffer b to
// have completed (stage precedes produce within a step).
// out[] is write-only during the kernel (plain stores, flushed at exit).
__global__ __launch_bounds__(256, 1)
void lstm_persist(const float* __restrict__ x_all,  // [1024][64][256]
                  const float* __restrict__ W4,     // [768][2048]
                  const float* __restrict__ b4,     // [2048]
                  float* out,                        // [1024][64][512] + hx + cx
                  u64* exch)                         // [2][64][512] tuples
{
    __shared__ float sH[ROWS * HROW_W];      // staged h_{t-1}, 18.4 KB
    __shared__ float sX[ROWS * XROW_W];      // staged x_t, 8.4 KB
    __shared__ float sP[ROWS * 64 * 20];     // K-split partials, 40 KB
    __shared__ float sC[ROWS * 16];          // c state, block-local

    const int tid = threadIdx.x;
    const int bid = blockIdx.x;
    const int rg  = bid & 7;                 // rowgrp
    const int cgb = bid >> 3;                // colgrp 0..31
    const int r0  = rg * ROWS;
    const int hc0 = cgb * 16;

    const int cg = tid & 15;                 // owns 4 z-cols
    const int kc = tid >> 4;                 // K-chunk 0..15
    const int l0 = cg * 4;
    const int gate = l0 >> 4;
    const int zc0 = gate * 512 + hc0 + (l0 & 15);

    // ---- precomputed staging offsets (t-invariant) ----
    int xL[2], xG[2];                        // x: 512 float4s, 2/thread
    #pragma unroll
    for (int s = 0; s < 2; ++s) {
        int j = tid + 256 * s;
        int row = j >> 6, kq = (j & 63) * 4;
        xL[s] = row * XROW_W + kq;
        xG[s] = (r0 + row) * DIN + kq;
    }
    int tL[16];                              // tuple -> LDS offsets, 16/thread
    #pragma unroll
    for (int s = 0; s < 16; ++s) {
        int l = tid + 256 * s;               // linear over 8 rows x 512 cols
        int ro = l >> 9, co = l & 511;
        tL[s] = ro * HROW_W + (co >> 5) * HCW + (co & 31);
    }
    const u64* exrd0 = exch + (size_t)r0 * HH + tid;   // + parity*EXQ + 256*s

    // ---- one-time: Wh slice (rows DIN + kc*32..+31, cols zc0..+3) ----
    float4 w0[8], w1[8], w2[8], w3[8];
    #pragma unroll
    for (int k4 = 0; k4 < 8; ++k4) {
        const float* base = W4 + (size_t)(DIN + kc * 32 + 4 * k4) * 2048 + zc0;
        float4 t0 = *(const float4*)(base);
        float4 t1 = *(const float4*)(base + 2048);
        float4 t2 = *(const float4*)(base + 4096);
        float4 t3 = *(const float4*)(base + 6144);
        w0[k4] = make_float4(t0.x, t1.x, t2.x, t3.x);
        w1[k4] = make_float4(t0.y, t1.y, t2.y, t3.y);
        w2[k4] = make_float4(t0.z, t1.z, t2.z, t3.z);
        w3[k4] = make_float4(t0.w, t1.w, t2.w, t3.w);
    }
    // ---- one-time: Wx slice (rows kc*16..+15, cols zc0..+3), row-major ----
    float4 wx[16];
    #pragma unroll
    for (int kk = 0; kk < 16; ++kk)
        wx[kk] = *(const float4*)(W4 + (size_t)(kc * 16 + kk) * 2048 + zc0);

    float bias0 = 0.f, bias1 = 0.f, bias2 = 0.f, bias3 = 0.f;
    int exO = 0;
    if (tid < 128) {
        sC[tid] = 0.f;
        int hc = tid & 15;
        int rr = tid >> 4;
        exO = (r0 + rr) * HH + hc0 + hc;     // producer tuple slot
        bias0 = b4[0 * 512 + hc0 + hc];
        bias1 = b4[1 * 512 + hc0 + hc];
        bias2 = b4[2 * 512 + hc0 + hc];
        bias3 = b4[3 * 512 + hc0 + hc];
    }

    // ---- pre-stage x_0 ----
    #pragma unroll
    for (int s = 0; s < 2; ++s)
        *(float4*)&sX[xL[s]] = *(const float4*)(x_all + xG[s]);
    __syncthreads();

    for (int t = 0; t < TT; ++t) {
        // ---- (A) issue x_{t+1} loads; x-part partials from sX ----
        const bool havex = (t + 1 < TT);
        float4 xr0, xr1;
        if (havex) {
            const float* xb = x_all + (size_t)(t + 1) * (BB * DIN);
            xr0 = *(const float4*)(xb + xG[0]);
            xr1 = *(const float4*)(xb + xG[1]);
        }
        float ac0[8], ac1[8], ac2[8], ac3[8];
        #pragma unroll
        for (int r = 0; r < ROWS; ++r) {
            const float* xp = &sX[r * XROW_W + kc * 16];
            float ax = 0.f, ay = 0.f, az = 0.f, aw = 0.f;
            #pragma unroll
            for (int q = 0; q < 4; ++q) {
                float4 x4 = *(const float4*)(xp + 4 * q);
                ax = fmaf(x4.x, wx[4*q+0].x, ax); ax = fmaf(x4.y, wx[4*q+1].x, ax);
                ax = fmaf(x4.z, wx[4*q+2].x, ax); ax = fmaf(x4.w, wx[4*q+3].x, ax);
                ay = fmaf(x4.x, wx[4*q+0].y, ay); ay = fmaf(x4.y, wx[4*q+1].y, ay);
                ay = fmaf(x4.z, wx[4*q+2].y, ay); ay = fmaf(x4.w, wx[4*q+3].y, ay);
                az = fmaf(x4.x, wx[4*q+0].z, az); az = fmaf(x4.y, wx[4*q+1].z, az);
                az = fmaf(x4.z, wx[4*q+2].z, az); az = fmaf(x4.w, wx[4*q+3].z, az);
                aw = fmaf(x4.x, wx[4*q+0].w, aw); aw = fmaf(x4.y, wx[4*q+1].w, aw);
                aw = fmaf(x4.z, wx[4*q+2].w, aw); aw = fmaf(x4.w, wx[4*q+3].w, aw);
            }
            ac0[r] = ax; ac1[r] = ay; ac2[r] = az; ac3[r] = aw;
        }
        __syncthreads();                                  // BAR1 (sX, sH safe)

        // ---- (C) tuple-read h_{t-1} (the sync) -> sH; refill sX ----
        if (t > 0) {
            const unsigned want = (unsigned)t;            // seq stored = t_prod+1
            const u64* tb = exrd0 + (size_t)((t & 1) ^ 1) * EXQ;
            u64 tv[16];
            #pragma unroll
            for (int s = 0; s < 16; ++s)
                tv[s] = __hip_atomic_load(tb + 256 * s, __ATOMIC_RELAXED,
                                          __HIP_MEMORY_SCOPE_AGENT);
            bool again;
            do {
                again = false;
                #pragma unroll
                for (int s = 0; s < 16; ++s) {
                    if ((unsigned)(tv[s] >> 32) != want) {
                        tv[s] = __hip_atomic_load(tb + 256 * s, __ATOMIC_RELAXED,
                                                  __HIP_MEMORY_SCOPE_AGENT);
                        again = true;
                    }
                }
            } while (again);
            #pragma unroll
            for (int s = 0; s < 16; ++s)
                sH[tL[s]] = __uint_as_float((unsigned)tv[s]);
        } else {
            #pragma unroll
            for (int s = 0; s < 16; ++s)
                sH[tL[s]] = 0.f;                          // h0 = zeros
        }
        if (havex) {
            *(float4*)&sX[xL[0]] = xr0;
            *(float4*)&sX[xL[1]] = xr1;
        }
        __syncthreads();                                  // BAR2 (sH, sX ready)

        // ---- (D) h-part: accumulate over this thread's 32-K ----
        #pragma unroll
        for (int r = 0; r < ROWS; ++r) {
            const float* hp = &sH[r * HROW_W + kc * HCW];
            float ax = ac0[r], ay = ac1[r], az = ac2[r], aw = ac3[r];
            #pragma unroll
            for (int k4 = 0; k4 < 8; ++k4) {
                float4 h4 = *(const float4*)(hp + 4 * k4);
                ax = fmaf(h4.x, w0[k4].x, ax); ax = fmaf(h4.y, w0[k4].y, ax);
                ax = fmaf(h4.z, w0[k4].z, ax); ax = fmaf(h4.w, w0[k4].w, ax);
                ay = fmaf(h4.x, w1[k4].x, ay); ay = fmaf(h4.y, w1[k4].y, ay);
                ay = fmaf(h4.z, w1[k4].z, ay); ay = fmaf(h4.w, w1[k4].w, ay);
                az = fmaf(h4.x, w2[k4].x, az); az = fmaf(h4.y, w2[k4].y, az);
                az = fmaf(h4.z, w2[k4].z, az); az = fmaf(h4.w, w2[k4].w, az);
                aw = fmaf(h4.x, w3[k4].x, aw); aw = fmaf(h4.y, w3[k4].y, aw);
                aw = fmaf(h4.z, w3[k4].z, aw); aw = fmaf(h4.w, w3[k4].w, aw);
            }
            float* pp = &sP[(r * 64 + l0) * 20];
            pp[0 * 20 + ((kc + 5 * cg + 0) & 15)] = ax;
            pp[1 * 20 + ((kc + 5 * cg + 1) & 15)] = ay;
            pp[2 * 20 + ((kc + 5 * cg + 2) & 15)] = az;
            pp[3 * 20 + ((kc + 5 * cg + 3) & 15)] = aw;
        }
        __syncthreads();                                  // BAR3 (sP ready)

        // ---- (F) reduce partials, gates, c/h update, publish tuples ----
        if (tid < 128) {
            int rr = tid >> 4;
            int hc = tid & 15;
            float z[4];
            #pragma unroll
            for (int g = 0; g < 4; ++g) {
                const float* pp = &sP[(rr * 64 + g * 16 + hc) * 20];
                float s = 0.f;
                #pragma unroll
                for (int q = 0; q < 4; ++q) {
                    int off = 4 * ((rr + q) & 3);
                    float4 a = *(const float4*)(pp + off);
                    s += ((a.x + a.y) + (a.z + a.w));
                }
                z[g] = s;
            }
            z[0] += bias0; z[1] += bias1; z[2] += bias2; z[3] += bias3;
            float f  = 1.f / (1.f + expf(-z[0]));
            float ii = 1.f / (1.f + expf(-z[1]));
            float gg = tanh_f(z[2]);
            float o  = 1.f / (1.f + expf(-z[3]));
            float cn = f * sC[rr * 16 + hc] + ii * gg;
            sC[rr * 16 + hc] = cn;
            float hn = o * tanh_f(cn);
            // graded history: plain store (write-only during kernel; flushed
            // by end-of-kernel system release)
            out[((size_t)t * BB + (r0 + rr)) * HH + hc0 + hc] = hn;
            if (t == TT - 1) {
                out[(size_t)TT * BB * HH + (size_t)(r0 + rr) * HH + hc0 + hc] = hn;            // hx
                out[(size_t)TT * BB * HH + BB * HH + (size_t)(r0 + rr) * HH + hc0 + hc] = cn;  // cx
            }
            // publish: self-validating tuple, fire-and-forget (no drain)
            u64 pk = ((u64)(unsigned)(t + 1) << 32) | (u64)__float_as_uint(hn);
            __hip_atomic_store(exch + (size_t)(t & 1) * EXQ + exO, pk,
                               __ATOMIC_RELAXED, __HIP_MEMORY_SCOPE_AGENT);
        }
        // no BAR4: next-iter BAR1/BAR2 cover all sX/sH/sP hazards
    }
}

extern "C" void kernel_launch(void* const* d_in, const int* in_sizes, int n_in,
                              void* d_out, int out_size, void* d_ws, size_t ws_size,
                              hipStream_t stream) {
    const float* x_all = (const float*)d_in[0];
    const float* W4    = (const float*)d_in[1];
    const float* b4    = (const float*)d_in[2];
    float* out = (float*)d_out;

    u64* exch = (u64*)d_ws;                  // [2][64][512] tuples, 512 KB

    hipMemsetAsync(d_ws, 0, 2 * (size_t)EXQ * sizeof(u64), stream);

    lstm_persist<<<dim3(256), dim3(256), 0, stream>>>(x_all, W4, b4, out, exch);
}